// Round 1
// baseline (617.243 us; speedup 1.0000x reference)
//
#include <hip/hip_runtime.h>
#include <hip/hip_bf16.h>
#include <cstdint>
#include <cstddef>

// ---------------------------------------------------------------------------
// FeatureExtractorGAT: 2-layer PyG-style GATConv on MI355X.
// Pipeline per call (all on `stream`, graph-capture safe):
//   memset deg=0
//   prep:    Wa1[2][4][8]  = W1 folded with att_{src,dst}1
//            Wa2[2][480]   = W2 folded with att_{src,dst}2
//   xh1:     [N,480] = x @ W1                  (flat float4 kernel)
//   a1:      [N,8]x2 = x @ Wa1                 (flat kernel)
//   CSR:     histogram -> 1-block scan -> atomic scatter (src list by dst)
//   gat1:    wave/node online-softmax aggregate + bias + ELU -> h[N,480]
//            fused: a2_src[n] = h[n]·Wa2_src, a2_dst[n] = h[n]·Wa2_dst
//   gemm2:   xh2[N,96] = h @ W2                (LDS-tiled f32 GEMM)
//   gat2:    wave/node online-softmax aggregate + b2 -> out[N,96]
// ---------------------------------------------------------------------------

__global__ void prep_kernel(const float* __restrict__ W1,
                            const float* __restrict__ as1, const float* __restrict__ ad1,
                            const float* __restrict__ W2,
                            const float* __restrict__ as2, const float* __restrict__ ad2,
                            float* __restrict__ wa1, float* __restrict__ wa2)
{
    int t = threadIdx.x;
    if (t < 480) {
        float accs = 0.f, accd = 0.f;
        #pragma unroll 4
        for (int c = 0; c < 96; ++c) {
            float w = W2[t * 96 + c];
            accs += w * as2[c];
            accd += w * ad2[c];
        }
        wa2[t]       = accs;
        wa2[480 + t] = accd;
    }
    if (t < 32) {
        int k = t >> 3, h = t & 7;
        float accs = 0.f, accd = 0.f;
        for (int c = 0; c < 60; ++c) {
            float w = W1[k * 480 + h * 60 + c];
            accs += w * as1[h * 60 + c];
            accd += w * ad1[h * 60 + c];
        }
        wa1[k * 8 + h]      = accs;
        wa1[32 + k * 8 + h] = accd;
    }
}

// xh1[n, j..j+3] : one float4 output per thread, 4-FMA each
__global__ void xh1_kernel(const float* __restrict__ x, const float* __restrict__ W1,
                           float* __restrict__ xh1, int N)
{
    int idx = blockIdx.x * blockDim.x + threadIdx.x;
    if (idx >= N * 120) return;
    int n = idx / 120;
    int j = (idx - n * 120) * 4;
    float4 xv = *(const float4*)(x + (size_t)n * 4);
    float4 w0 = *(const float4*)(W1 + j);
    float4 w1 = *(const float4*)(W1 + 480 + j);
    float4 w2 = *(const float4*)(W1 + 960 + j);
    float4 w3 = *(const float4*)(W1 + 1440 + j);
    float4 o;
    o.x = xv.x * w0.x + xv.y * w1.x + xv.z * w2.x + xv.w * w3.x;
    o.y = xv.x * w0.y + xv.y * w1.y + xv.z * w2.y + xv.w * w3.y;
    o.z = xv.x * w0.z + xv.y * w1.z + xv.z * w2.z + xv.w * w3.z;
    o.w = xv.x * w0.w + xv.y * w1.w + xv.z * w2.w + xv.w * w3.w;
    *(float4*)(xh1 + (size_t)n * 480 + j) = o;
}

__global__ void a1_kernel(const float* __restrict__ x, const float* __restrict__ wa1,
                          float* __restrict__ a_s1, float* __restrict__ a_d1, int N)
{
    int n = blockIdx.x * blockDim.x + threadIdx.x;
    if (n >= N) return;
    float4 xv = *(const float4*)(x + (size_t)n * 4);
    #pragma unroll
    for (int h = 0; h < 8; ++h) {
        float as = xv.x * wa1[h] + xv.y * wa1[8 + h] + xv.z * wa1[16 + h] + xv.w * wa1[24 + h];
        float ad = xv.x * wa1[32 + h] + xv.y * wa1[40 + h] + xv.z * wa1[48 + h] + xv.w * wa1[56 + h];
        a_s1[n * 8 + h] = as;
        a_d1[n * 8 + h] = ad;
    }
}

__global__ void degree_kernel(const int* __restrict__ ei, int E, int N, int* __restrict__ deg)
{
    int e = blockIdx.x * blockDim.x + threadIdx.x;
    if (e >= E + N) return;
    int d = (e < E) ? ei[E + e] : (e - E);
    atomicAdd(&deg[d], 1);
}

__global__ __launch_bounds__(1024) void scan_kernel(const int* __restrict__ deg,
                                                    int* __restrict__ row_ptr,
                                                    int* __restrict__ cursor, int N)
{
    __shared__ int wsum[16];
    int t = threadIdx.x;
    int lane = t & 63, wid = t >> 6;
    int running = 0;
    int nchunk = (N + 1023) / 1024;
    for (int c = 0; c < nchunk; ++c) {
        int i = c * 1024 + t;
        int v = (i < N) ? deg[i] : 0;
        int x = v;
        #pragma unroll
        for (int off = 1; off < 64; off <<= 1) {
            int y = __shfl_up(x, off, 64);
            if (lane >= off) x += y;
        }
        if (lane == 63) wsum[wid] = x;
        __syncthreads();
        if (wid == 0) {
            int wv = (lane < 16) ? wsum[lane] : 0;
            #pragma unroll
            for (int off = 1; off < 16; off <<= 1) {
                int y = __shfl_up(wv, off, 64);
                if (lane >= off) wv += y;
            }
            if (lane < 16) wsum[lane] = wv;
        }
        __syncthreads();
        int wprefix = (wid > 0) ? wsum[wid - 1] : 0;
        int excl = running + wprefix + x - v;
        if (i < N) { row_ptr[i] = excl; cursor[i] = excl; }
        running += wsum[15];
        __syncthreads();
    }
    if (t == 0) row_ptr[N] = running;
}

__global__ void scatter_kernel(const int* __restrict__ ei, int E, int N,
                               int* __restrict__ cursor, int* __restrict__ csr)
{
    int e = blockIdx.x * blockDim.x + threadIdx.x;
    if (e >= E + N) return;
    int s, d;
    if (e < E) { s = ei[e]; d = ei[E + e]; } else { s = d = e - E; }
    int pos = atomicAdd(&cursor[d], 1);
    csr[pos] = s;
}

// One wave per destination node. Per lane: 4 float2 output pairs
// (j = 2p, 2p+1 for p = lane, lane+64, lane+128, lane+192[lane<48]);
// each pair lies entirely within one head h = p/30. Online softmax with
// per-pair running (m, s). Fused bias+ELU and the layer-2 attention dots.
__global__ __launch_bounds__(256) void gat1_edge_kernel(
    const int* __restrict__ row_ptr, const int* __restrict__ csr,
    const float* __restrict__ a_s1, const float* __restrict__ a_d1,
    const float* __restrict__ xh1, const float* __restrict__ wa2,
    const float* __restrict__ b1,
    float* __restrict__ hout, float* __restrict__ a2s, float* __restrict__ a2d, int N)
{
    int gid = blockIdx.x * blockDim.x + threadIdx.x;
    int node = gid >> 6;
    if (node >= N) return;
    int lane = threadIdx.x & 63;
    bool has3 = lane < 48;
    int p0 = lane, p1 = lane + 64, p2 = lane + 128, p3 = has3 ? (lane + 192) : 0;
    int h0 = p0 / 30, h1 = p1 / 30, h2 = p2 / 30, h3 = p3 / 30;
    const float* adp = a_d1 + (size_t)node * 8;
    float ad0 = adp[h0], ad1v = adp[h1], ad2v = adp[h2], ad3v = adp[h3];
    float m0 = -1e30f, m1 = -1e30f, m2 = -1e30f, m3 = -1e30f;
    float s0 = 0.f, s1 = 0.f, s2 = 0.f, s3 = 0.f;
    float2 acc0 = {0.f, 0.f}, acc1 = {0.f, 0.f}, acc2 = {0.f, 0.f}, acc3 = {0.f, 0.f};

    int beg = row_ptr[node], end = row_ptr[node + 1];
    for (int e = beg; e < end; ++e) {
        int src = csr[e];
        const float*  asp = a_s1 + (size_t)src * 8;
        const float2* gp  = (const float2*)(xh1 + (size_t)src * 480);
        float2 g0 = gp[p0], g1 = gp[p1], g2 = gp[p2], g3 = gp[p3];
        {
            float ev = asp[h0] + ad0;  ev = ev > 0.f ? ev : 0.2f * ev;
            float nm = fmaxf(m0, ev);
            float sc = __expf(m0 - nm), pc = __expf(ev - nm);
            s0 = s0 * sc + pc; m0 = nm;
            acc0.x = acc0.x * sc + pc * g0.x;  acc0.y = acc0.y * sc + pc * g0.y;
        }
        {
            float ev = asp[h1] + ad1v; ev = ev > 0.f ? ev : 0.2f * ev;
            float nm = fmaxf(m1, ev);
            float sc = __expf(m1 - nm), pc = __expf(ev - nm);
            s1 = s1 * sc + pc; m1 = nm;
            acc1.x = acc1.x * sc + pc * g1.x;  acc1.y = acc1.y * sc + pc * g1.y;
        }
        {
            float ev = asp[h2] + ad2v; ev = ev > 0.f ? ev : 0.2f * ev;
            float nm = fmaxf(m2, ev);
            float sc = __expf(m2 - nm), pc = __expf(ev - nm);
            s2 = s2 * sc + pc; m2 = nm;
            acc2.x = acc2.x * sc + pc * g2.x;  acc2.y = acc2.y * sc + pc * g2.y;
        }
        {
            float ev = asp[h3] + ad3v; ev = ev > 0.f ? ev : 0.2f * ev;
            float nm = fmaxf(m3, ev);
            float sc = __expf(m3 - nm), pc = __expf(ev - nm);
            s3 = s3 * sc + pc; m3 = nm;
            acc3.x = acc3.x * sc + pc * g3.x;  acc3.y = acc3.y * sc + pc * g3.y;
        }
    }

    float2 o0, o1, o2, o3;
    {
        float inv = 1.f / s0;
        o0.x = acc0.x * inv + b1[2 * p0];     o0.y = acc0.y * inv + b1[2 * p0 + 1];
        o0.x = o0.x > 0.f ? o0.x : expm1f(o0.x);  o0.y = o0.y > 0.f ? o0.y : expm1f(o0.y);
    }
    {
        float inv = 1.f / s1;
        o1.x = acc1.x * inv + b1[2 * p1];     o1.y = acc1.y * inv + b1[2 * p1 + 1];
        o1.x = o1.x > 0.f ? o1.x : expm1f(o1.x);  o1.y = o1.y > 0.f ? o1.y : expm1f(o1.y);
    }
    {
        float inv = 1.f / s2;
        o2.x = acc2.x * inv + b1[2 * p2];     o2.y = acc2.y * inv + b1[2 * p2 + 1];
        o2.x = o2.x > 0.f ? o2.x : expm1f(o2.x);  o2.y = o2.y > 0.f ? o2.y : expm1f(o2.y);
    }
    {
        float inv = 1.f / s3;
        o3.x = acc3.x * inv + b1[2 * p3];     o3.y = acc3.y * inv + b1[2 * p3 + 1];
        o3.x = o3.x > 0.f ? o3.x : expm1f(o3.x);  o3.y = o3.y > 0.f ? o3.y : expm1f(o3.y);
    }

    float* hp = hout + (size_t)node * 480;
    *(float2*)(hp + 2 * p0) = o0;
    *(float2*)(hp + 2 * p1) = o1;
    *(float2*)(hp + 2 * p2) = o2;
    if (has3) *(float2*)(hp + 2 * p3) = o3;

    float psrc = o0.x * wa2[2 * p0] + o0.y * wa2[2 * p0 + 1]
               + o1.x * wa2[2 * p1] + o1.y * wa2[2 * p1 + 1]
               + o2.x * wa2[2 * p2] + o2.y * wa2[2 * p2 + 1];
    float pdst = o0.x * wa2[480 + 2 * p0] + o0.y * wa2[480 + 2 * p0 + 1]
               + o1.x * wa2[480 + 2 * p1] + o1.y * wa2[480 + 2 * p1 + 1]
               + o2.x * wa2[480 + 2 * p2] + o2.y * wa2[480 + 2 * p2 + 1];
    if (has3) {
        psrc += o3.x * wa2[2 * p3] + o3.y * wa2[2 * p3 + 1];
        pdst += o3.x * wa2[480 + 2 * p3] + o3.y * wa2[480 + 2 * p3 + 1];
    }
    #pragma unroll
    for (int off = 32; off; off >>= 1) {
        psrc += __shfl_xor(psrc, off);
        pdst += __shfl_xor(pdst, off);
    }
    if (lane == 0) { a2s[node] = psrc; a2d[node] = pdst; }
}

// xh2[N,96] = h[N,480] @ W2[480,96]; 128-node x 96-col tile per block,
// 256 threads, 8x6 register tile per thread, k staged in 32-chunks via LDS.
__global__ __launch_bounds__(256) void gemm2_kernel(
    const float* __restrict__ h, const float* __restrict__ W2,
    float* __restrict__ xh2, int N)
{
    __shared__ float hs[128][36];
    __shared__ float ws[32][96];
    int t = threadIdx.x;
    int nbase = blockIdx.x * 128;
    int tx = t & 15, ty = t >> 4;
    float acc[8][6];
    #pragma unroll
    for (int i = 0; i < 8; ++i)
        #pragma unroll
        for (int j = 0; j < 6; ++j) acc[i][j] = 0.f;

    for (int k0 = 0; k0 < 480; k0 += 32) {
        #pragma unroll
        for (int i = 0; i < 3; ++i) {
            int f = i * 256 + t;
            int kk = f / 24, c4 = f % 24;
            float4 v = *(const float4*)(W2 + (size_t)(k0 + kk) * 96 + c4 * 4);
            *(float4*)&ws[kk][c4 * 4] = v;
        }
        #pragma unroll
        for (int i = 0; i < 4; ++i) {
            int f = i * 256 + t;
            int node = f >> 3, k4 = f & 7;
            int gn = nbase + node; if (gn > N - 1) gn = N - 1;
            float4 v = *(const float4*)(h + (size_t)gn * 480 + k0 + k4 * 4);
            *(float4*)&hs[node][k4 * 4] = v;
        }
        __syncthreads();
        #pragma unroll
        for (int kk = 0; kk < 32; ++kk) {
            float hv[8], wv[6];
            #pragma unroll
            for (int i = 0; i < 8; ++i) hv[i] = hs[ty * 8 + i][kk];
            #pragma unroll
            for (int j = 0; j < 6; ++j) wv[j] = ws[kk][tx * 6 + j];
            #pragma unroll
            for (int i = 0; i < 8; ++i)
                #pragma unroll
                for (int j = 0; j < 6; ++j)
                    acc[i][j] += hv[i] * wv[j];
        }
        __syncthreads();
    }
    #pragma unroll
    for (int i = 0; i < 8; ++i) {
        int gn = nbase + ty * 8 + i;
        if (gn < N) {
            #pragma unroll
            for (int j = 0; j < 6; ++j)
                xh2[(size_t)gn * 96 + tx * 6 + j] = acc[i][j];
        }
    }
}

// One wave per node; lane handles c=lane and (lane<32) c=lane+64.
__global__ __launch_bounds__(256) void gat2_edge_kernel(
    const int* __restrict__ row_ptr, const int* __restrict__ csr,
    const float* __restrict__ a_s2, const float* __restrict__ a_d2,
    const float* __restrict__ xh2, const float* __restrict__ b2,
    float* __restrict__ out, int N)
{
    int gid = blockIdx.x * blockDim.x + threadIdx.x;
    int node = gid >> 6;
    if (node >= N) return;
    int lane = threadIdx.x & 63;
    bool hasc1 = lane < 32;
    int c0 = lane, c1 = 64 + lane;
    float adv = a_d2[node];
    float m = -1e30f, s = 0.f, acc0 = 0.f, acc1 = 0.f;
    int beg = row_ptr[node], end = row_ptr[node + 1];
    for (int e = beg; e < end; ++e) {
        int src = csr[e];
        float ev = a_s2[src] + adv;
        ev = ev > 0.f ? ev : 0.2f * ev;
        float nm = fmaxf(m, ev);
        float sc = __expf(m - nm);
        float pc = __expf(ev - nm);
        s = s * sc + pc; m = nm;
        const float* gp = xh2 + (size_t)src * 96;
        acc0 = acc0 * sc + pc * gp[c0];
        if (hasc1) acc1 = acc1 * sc + pc * gp[c1];
    }
    float inv = 1.f / s;
    out[(size_t)node * 96 + c0] = acc0 * inv + b2[c0];
    if (hasc1) out[(size_t)node * 96 + c1] = acc1 * inv + b2[c1];
}

extern "C" void kernel_launch(void* const* d_in, const int* in_sizes, int n_in,
                              void* d_out, int out_size, void* d_ws, size_t ws_size,
                              hipStream_t stream)
{
    const float* x   = (const float*)d_in[0];
    const int*   ei  = (const int*)  d_in[1];
    const float* W1  = (const float*)d_in[2];
    const float* as1 = (const float*)d_in[3];
    const float* ad1 = (const float*)d_in[4];
    const float* b1  = (const float*)d_in[5];
    const float* W2  = (const float*)d_in[6];
    const float* as2 = (const float*)d_in[7];
    const float* ad2 = (const float*)d_in[8];
    const float* b2  = (const float*)d_in[9];
    float* out = (float*)d_out;

    int N  = in_sizes[0] / 4;   // 50000
    int E  = in_sizes[1] / 2;   // 800000
    int EP = E + N;             // + self-loops

    float* f = (float*)d_ws;
    float* xh1  = f;  f += (size_t)N * 480;
    float* hbuf = f;  f += (size_t)N * 480;
    float* xh2  = f;  f += (size_t)N * 96;
    float* a_s1 = f;  f += (size_t)N * 8;
    float* a_d1 = f;  f += (size_t)N * 8;
    float* a_s2 = f;  f += N;
    float* a_d2 = f;  f += N;
    float* wa1  = f;  f += 64;
    float* wa2  = f;  f += 960;
    int* ip      = (int*)f;
    int* row_ptr = ip;  ip += N + 1;
    int* deg     = ip;  ip += N;
    int* cursor  = ip;  ip += N;
    int* csr     = ip;  ip += EP;

    size_t needed = (size_t)((char*)ip - (char*)d_ws);
    if (needed > ws_size) return;  // scratch too small -> leave output unwritten (loud failure)

    hipMemsetAsync(deg, 0, (size_t)N * sizeof(int), stream);
    prep_kernel<<<1, 512, 0, stream>>>(W1, as1, ad1, W2, as2, ad2, wa1, wa2);
    xh1_kernel<<<(N * 120 + 255) / 256, 256, 0, stream>>>(x, W1, xh1, N);
    a1_kernel<<<(N + 255) / 256, 256, 0, stream>>>(x, wa1, a_s1, a_d1, N);
    degree_kernel<<<(EP + 255) / 256, 256, 0, stream>>>(ei, E, N, deg);
    scan_kernel<<<1, 1024, 0, stream>>>(deg, row_ptr, cursor, N);
    scatter_kernel<<<(EP + 255) / 256, 256, 0, stream>>>(ei, E, N, cursor, csr);
    gat1_edge_kernel<<<(N * 64 + 255) / 256, 256, 0, stream>>>(
        row_ptr, csr, a_s1, a_d1, xh1, wa2, b1, hbuf, a_s2, a_d2, N);
    gemm2_kernel<<<(N + 127) / 128, 256, 0, stream>>>(hbuf, W2, xh2, N);
    gat2_edge_kernel<<<(N * 64 + 255) / 256, 256, 0, stream>>>(
        row_ptr, csr, a_s2, a_d2, xh2, b2, out, N);
}

// Round 3
// 599.899 us; speedup vs baseline: 1.0289x; 1.0289x over previous
//
#include <hip/hip_runtime.h>
#include <hip/hip_bf16.h>
#include <hip/hip_fp16.h>
#include <cstdint>
#include <cstddef>

// ---------------------------------------------------------------------------
// FeatureExtractorGAT, round 2 (resubmitted unchanged; R2 bench was an infra
// failure — UnresponsiveContainer — so these changes were never measured).
// Changes vs R1:
//  - xh1, xh2 stored fp16 (halves the dominant random-gather traffic).
//  - gat layers split into phases: edge-logit exp+sum (A), normalized
//    weighted gather-accumulate (B). No online-softmax rescale, no exp in
//    the heavy loop. (No max subtraction: |logits| <~4, exp safe in f32,
//    mathematically identical to the reference's shifted softmax.)
//  - B1 reads 8 contiguous fp16 features per lane with one 16B load
//    (60 active lanes cover the 480-wide row).
//  - single-block scan now 49-elems/thread (3 passes), not 49 serial chunks.
// ---------------------------------------------------------------------------

__global__ void prep_kernel(const float* __restrict__ W1,
                            const float* __restrict__ as1, const float* __restrict__ ad1,
                            const float* __restrict__ W2,
                            const float* __restrict__ as2, const float* __restrict__ ad2,
                            float* __restrict__ wa1, float* __restrict__ wa2)
{
    int t = threadIdx.x;
    if (t < 480) {
        float accs = 0.f, accd = 0.f;
        #pragma unroll 4
        for (int c = 0; c < 96; ++c) {
            float w = W2[t * 96 + c];
            accs += w * as2[c];
            accd += w * ad2[c];
        }
        wa2[t]       = accs;
        wa2[480 + t] = accd;
    }
    if (t < 32) {
        int k = t >> 3, h = t & 7;
        float accs = 0.f, accd = 0.f;
        for (int c = 0; c < 60; ++c) {
            float w = W1[k * 480 + h * 60 + c];
            accs += w * as1[h * 60 + c];
            accd += w * ad1[h * 60 + c];
        }
        wa1[k * 8 + h]      = accs;
        wa1[32 + k * 8 + h] = accd;
    }
}

// xh1h[n, j..j+3] (fp16): one float4-worth per thread
__global__ void xh1_kernel(const float* __restrict__ x, const float* __restrict__ W1,
                           __half* __restrict__ xh1h, int N)
{
    int idx = blockIdx.x * blockDim.x + threadIdx.x;
    if (idx >= N * 120) return;
    int n = idx / 120;
    int j = (idx - n * 120) * 4;
    float4 xv = *(const float4*)(x + (size_t)n * 4);
    float4 w0 = *(const float4*)(W1 + j);
    float4 w1 = *(const float4*)(W1 + 480 + j);
    float4 w2 = *(const float4*)(W1 + 960 + j);
    float4 w3 = *(const float4*)(W1 + 1440 + j);
    float ox = xv.x * w0.x + xv.y * w1.x + xv.z * w2.x + xv.w * w3.x;
    float oy = xv.x * w0.y + xv.y * w1.y + xv.z * w2.y + xv.w * w3.y;
    float oz = xv.x * w0.z + xv.y * w1.z + xv.z * w2.z + xv.w * w3.z;
    float ow = xv.x * w0.w + xv.y * w1.w + xv.z * w2.w + xv.w * w3.w;
    __half2* dst = (__half2*)(xh1h + (size_t)n * 480 + j);
    dst[0] = __floats2half2_rn(ox, oy);
    dst[1] = __floats2half2_rn(oz, ow);
}

__global__ void a1_kernel(const float* __restrict__ x, const float* __restrict__ wa1,
                          float* __restrict__ a_s1, float* __restrict__ a_d1, int N)
{
    int n = blockIdx.x * blockDim.x + threadIdx.x;
    if (n >= N) return;
    float4 xv = *(const float4*)(x + (size_t)n * 4);
    #pragma unroll
    for (int h = 0; h < 8; ++h) {
        float as = xv.x * wa1[h] + xv.y * wa1[8 + h] + xv.z * wa1[16 + h] + xv.w * wa1[24 + h];
        float ad = xv.x * wa1[32 + h] + xv.y * wa1[40 + h] + xv.z * wa1[48 + h] + xv.w * wa1[56 + h];
        a_s1[n * 8 + h] = as;
        a_d1[n * 8 + h] = ad;
    }
}

__global__ void degree_kernel(const int* __restrict__ ei, int E, int N, int* __restrict__ deg)
{
    int e = blockIdx.x * blockDim.x + threadIdx.x;
    if (e >= E + N) return;
    int d = (e < E) ? ei[E + e] : (e - E);
    atomicAdd(&deg[d], 1);
}

// 1024 threads, ~49 contiguous elems per thread, 3 passes (sum, scan, write)
__global__ __launch_bounds__(1024) void scan2_kernel(const int* __restrict__ deg,
                                                     int* __restrict__ row_ptr,
                                                     int* __restrict__ cursor, int N)
{
    __shared__ int wsum[16];
    int t = threadIdx.x;
    int lane = t & 63, wid = t >> 6;
    int EPT = (N + 1023) >> 10;
    int base = t * EPT;
    int local = 0;
    for (int i = 0; i < EPT; ++i) {
        int idx = base + i;
        if (idx < N) local += deg[idx];
    }
    int x = local;
    #pragma unroll
    for (int off = 1; off < 64; off <<= 1) {
        int y = __shfl_up(x, off, 64);
        if (lane >= off) x += y;
    }
    if (lane == 63) wsum[wid] = x;
    __syncthreads();
    if (wid == 0) {
        int wv = (lane < 16) ? wsum[lane] : 0;
        #pragma unroll
        for (int off = 1; off < 16; off <<= 1) {
            int y = __shfl_up(wv, off, 64);
            if (lane >= off) wv += y;
        }
        if (lane < 16) wsum[lane] = wv;
    }
    __syncthreads();
    int run = (wid > 0 ? wsum[wid - 1] : 0) + x - local;  // exclusive prefix
    for (int i = 0; i < EPT; ++i) {
        int idx = base + i;
        if (idx < N) {
            row_ptr[idx] = run;
            cursor[idx]  = run;
            run += deg[idx];
        }
    }
    if (t == 1023) row_ptr[N] = run;
}

__global__ void scatter_kernel(const int* __restrict__ ei, int E, int N,
                               int* __restrict__ cursor, int* __restrict__ csr)
{
    int e = blockIdx.x * blockDim.x + threadIdx.x;
    if (e >= E + N) return;
    int s, d;
    if (e < E) { s = ei[e]; d = ei[E + e]; } else { s = d = e - E; }
    int pos = atomicAdd(&cursor[d], 1);
    csr[pos] = s;
}

// ---- GAT layer 1, phase A: p[e][h] = exp(leaky(a_s[src]+a_d[dst])), per-node sums
__global__ __launch_bounds__(256) void gat1_pass_a(
    const int* __restrict__ row_ptr, const int* __restrict__ csr,
    const float* __restrict__ a_s1, const float* __restrict__ a_d1,
    float* __restrict__ pbuf1, float* __restrict__ inv1, int N)
{
    int gid = blockIdx.x * blockDim.x + threadIdx.x;
    int node = gid >> 6;
    if (node >= N) return;
    int lane = threadIdx.x & 63;
    float4 adA = *(const float4*)(a_d1 + (size_t)node * 8);
    float4 adB = *(const float4*)(a_d1 + (size_t)node * 8 + 4);
    float ad[8] = {adA.x, adA.y, adA.z, adA.w, adB.x, adB.y, adB.z, adB.w};
    float s[8] = {0.f, 0.f, 0.f, 0.f, 0.f, 0.f, 0.f, 0.f};
    int beg = row_ptr[node], end = row_ptr[node + 1];
    for (int e = beg + lane; e < end; e += 64) {
        int src = csr[e];
        float4 asA = *(const float4*)(a_s1 + (size_t)src * 8);
        float4 asB = *(const float4*)(a_s1 + (size_t)src * 8 + 4);
        float as[8] = {asA.x, asA.y, asA.z, asA.w, asB.x, asB.y, asB.z, asB.w};
        float p[8];
        #pragma unroll
        for (int h = 0; h < 8; ++h) {
            float ev = as[h] + ad[h];
            ev = ev > 0.f ? ev : 0.2f * ev;
            float pv = __expf(ev);
            p[h] = pv;
            s[h] += pv;
        }
        float4* pp = (float4*)(pbuf1 + (size_t)e * 8);
        pp[0] = make_float4(p[0], p[1], p[2], p[3]);
        pp[1] = make_float4(p[4], p[5], p[6], p[7]);
    }
    #pragma unroll
    for (int h = 0; h < 8; ++h) {
        #pragma unroll
        for (int off = 32; off; off >>= 1) s[h] += __shfl_xor(s[h], off);
    }
    if (lane == 0) {
        float* ip = inv1 + (size_t)node * 8;
        #pragma unroll
        for (int h = 0; h < 8; ++h) ip[h] = 1.f / (s[h] + 1e-16f);
    }
}

// ---- GAT layer 1, phase B: weighted aggregate + bias + ELU + layer-2 dots.
// Lane l<60 owns 8 contiguous features [8l, 8l+8) -> one 16B fp16 load/edge.
__global__ __launch_bounds__(256) void gat1_pass_b(
    const int* __restrict__ row_ptr, const int* __restrict__ csr,
    const float* __restrict__ pbuf1, const float* __restrict__ inv1,
    const __half* __restrict__ xh1h, const float* __restrict__ wa2,
    const float* __restrict__ b1,
    float* __restrict__ hout, float* __restrict__ a2s, float* __restrict__ a2d, int N)
{
    int gid = blockIdx.x * blockDim.x + threadIdx.x;
    int node = gid >> 6;
    if (node >= N) return;
    int lane = threadIdx.x & 63;
    bool act = lane < 60;
    int col0 = act ? lane * 8 : 0;
    int hA = col0 / 60;
    int hB = (col0 + 7) / 60;
    int sb = 60 * (hA + 1) - col0;  if (sb > 8) sb = 8;  // cols j<sb belong to head hA
    const float* ip = inv1 + (size_t)node * 8;
    float invA = ip[hA], invB = ip[hB];

    float acc[8];
    #pragma unroll
    for (int j = 0; j < 8; ++j) acc[j] = 0.f;

    int beg = row_ptr[node], end = row_ptr[node + 1];
    for (int e = beg; e < end; ++e) {
        int src = csr[e];
        const float* pr = pbuf1 + (size_t)e * 8;
        float cA = pr[hA] * invA;
        float cB = pr[hB] * invB;
        uint4 raw = *(const uint4*)(xh1h + (size_t)src * 480 + col0);
        float2 f0 = __half22float2(*(const __half2*)&raw.x);
        float2 f1 = __half22float2(*(const __half2*)&raw.y);
        float2 f2 = __half22float2(*(const __half2*)&raw.z);
        float2 f3 = __half22float2(*(const __half2*)&raw.w);
        float g[8] = {f0.x, f0.y, f1.x, f1.y, f2.x, f2.y, f3.x, f3.y};
        #pragma unroll
        for (int j = 0; j < 8; ++j) {
            float c = (j < sb) ? cA : cB;
            acc[j] += c * g[j];
        }
    }

    float psrc = 0.f, pdst = 0.f;
    if (act) {
        float o[8];
        #pragma unroll
        for (int j = 0; j < 8; ++j) {
            float v = acc[j] + b1[col0 + j];
            o[j] = v > 0.f ? v : expm1f(v);
        }
        float4* hp = (float4*)(hout + (size_t)node * 480 + col0);
        hp[0] = make_float4(o[0], o[1], o[2], o[3]);
        hp[1] = make_float4(o[4], o[5], o[6], o[7]);
        #pragma unroll
        for (int j = 0; j < 8; ++j) {
            psrc += o[j] * wa2[col0 + j];
            pdst += o[j] * wa2[480 + col0 + j];
        }
    }
    #pragma unroll
    for (int off = 32; off; off >>= 1) {
        psrc += __shfl_xor(psrc, off);
        pdst += __shfl_xor(pdst, off);
    }
    if (lane == 0) { a2s[node] = psrc; a2d[node] = pdst; }
}

// ---- GAT layer 2, phase A (1 head)
__global__ __launch_bounds__(256) void gat2_pass_a(
    const int* __restrict__ row_ptr, const int* __restrict__ csr,
    const float* __restrict__ a_s2, const float* __restrict__ a_d2,
    float* __restrict__ pbuf2, float* __restrict__ inv2, int N)
{
    int gid = blockIdx.x * blockDim.x + threadIdx.x;
    int node = gid >> 6;
    if (node >= N) return;
    int lane = threadIdx.x & 63;
    float adv = a_d2[node];
    float s = 0.f;
    int beg = row_ptr[node], end = row_ptr[node + 1];
    for (int e = beg + lane; e < end; e += 64) {
        int src = csr[e];
        float ev = a_s2[src] + adv;
        ev = ev > 0.f ? ev : 0.2f * ev;
        float pv = __expf(ev);
        pbuf2[e] = pv;
        s += pv;
    }
    #pragma unroll
    for (int off = 32; off; off >>= 1) s += __shfl_xor(s, off);
    if (lane == 0) inv2[node] = 1.f / (s + 1e-16f);
}

// ---- GAT layer 2, phase B: lane<48 owns cols {2l, 2l+1} (one half2/edge)
__global__ __launch_bounds__(256) void gat2_pass_b(
    const int* __restrict__ row_ptr, const int* __restrict__ csr,
    const float* __restrict__ pbuf2, const float* __restrict__ inv2,
    const __half* __restrict__ xh2h, const float* __restrict__ b2,
    float* __restrict__ out, int N)
{
    int gid = blockIdx.x * blockDim.x + threadIdx.x;
    int node = gid >> 6;
    if (node >= N) return;
    int lane = threadIdx.x & 63;
    bool act = lane < 48;
    float invv = inv2[node];
    float ax = 0.f, ay = 0.f;
    int beg = row_ptr[node], end = row_ptr[node + 1];
    for (int e = beg; e < end; ++e) {
        int src = csr[e];
        float c = pbuf2[e] * invv;
        if (act) {
            __half2 g = ((const __half2*)(xh2h + (size_t)src * 96))[lane];
            float2 fg = __half22float2(g);
            ax += c * fg.x;
            ay += c * fg.y;
        }
    }
    if (act) {
        out[(size_t)node * 96 + 2 * lane]     = ax + b2[2 * lane];
        out[(size_t)node * 96 + 2 * lane + 1] = ay + b2[2 * lane + 1];
    }
}

// xh2h[N,96] = h[N,480] @ W2[480,96], fp16 out
__global__ __launch_bounds__(256) void gemm2_kernel(
    const float* __restrict__ h, const float* __restrict__ W2,
    __half* __restrict__ xh2h, int N)
{
    __shared__ float hs[128][36];
    __shared__ float ws[32][96];
    int t = threadIdx.x;
    int nbase = blockIdx.x * 128;
    int tx = t & 15, ty = t >> 4;
    float acc[8][6];
    #pragma unroll
    for (int i = 0; i < 8; ++i)
        #pragma unroll
        for (int j = 0; j < 6; ++j) acc[i][j] = 0.f;

    for (int k0 = 0; k0 < 480; k0 += 32) {
        #pragma unroll
        for (int i = 0; i < 3; ++i) {
            int f = i * 256 + t;
            int kk = f / 24, c4 = f % 24;
            float4 v = *(const float4*)(W2 + (size_t)(k0 + kk) * 96 + c4 * 4);
            *(float4*)&ws[kk][c4 * 4] = v;
        }
        #pragma unroll
        for (int i = 0; i < 4; ++i) {
            int f = i * 256 + t;
            int node = f >> 3, k4 = f & 7;
            int gn = nbase + node; if (gn > N - 1) gn = N - 1;
            float4 v = *(const float4*)(h + (size_t)gn * 480 + k0 + k4 * 4);
            *(float4*)&hs[node][k4 * 4] = v;
        }
        __syncthreads();
        #pragma unroll
        for (int kk = 0; kk < 32; ++kk) {
            float hv[8], wv[6];
            #pragma unroll
            for (int i = 0; i < 8; ++i) hv[i] = hs[ty * 8 + i][kk];
            #pragma unroll
            for (int j = 0; j < 6; ++j) wv[j] = ws[kk][tx * 6 + j];
            #pragma unroll
            for (int i = 0; i < 8; ++i)
                #pragma unroll
                for (int j = 0; j < 6; ++j)
                    acc[i][j] += hv[i] * wv[j];
        }
        __syncthreads();
    }
    #pragma unroll
    for (int i = 0; i < 8; ++i) {
        int gn = nbase + ty * 8 + i;
        if (gn < N) {
            #pragma unroll
            for (int j = 0; j < 6; ++j)
                xh2h[(size_t)gn * 96 + tx * 6 + j] = __float2half(acc[i][j]);
        }
    }
}

extern "C" void kernel_launch(void* const* d_in, const int* in_sizes, int n_in,
                              void* d_out, int out_size, void* d_ws, size_t ws_size,
                              hipStream_t stream)
{
    const float* x   = (const float*)d_in[0];
    const int*   ei  = (const int*)  d_in[1];
    const float* W1  = (const float*)d_in[2];
    const float* as1 = (const float*)d_in[3];
    const float* ad1 = (const float*)d_in[4];
    const float* b1  = (const float*)d_in[5];
    const float* W2  = (const float*)d_in[6];
    const float* as2 = (const float*)d_in[7];
    const float* ad2 = (const float*)d_in[8];
    const float* b2  = (const float*)d_in[9];
    float* out = (float*)d_out;

    int N  = in_sizes[0] / 4;   // 50000
    int E  = in_sizes[1] / 2;   // 800000
    int EP = E + N;

    float* f = (float*)d_ws;
    float* hbuf  = f;  f += (size_t)N * 480;
    float* a_s1  = f;  f += (size_t)N * 8;
    float* a_d1  = f;  f += (size_t)N * 8;
    float* inv1  = f;  f += (size_t)N * 8;
    float* a_s2  = f;  f += N;
    float* a_d2  = f;  f += N;
    float* inv2  = f;  f += N;
    float* wa1   = f;  f += 64;
    float* wa2   = f;  f += 960;
    float* pbuf1 = f;  f += (size_t)EP * 8;
    float* pbuf2 = f;  f += EP;
    __half* xh1h = (__half*)f;
    __half* hp   = xh1h + (size_t)N * 480;
    __half* xh2h = hp;   hp += (size_t)N * 96;
    int* ip      = (int*)hp;
    int* row_ptr = ip;  ip += N + 1;
    int* deg     = ip;  ip += N;
    int* cursor  = ip;  ip += N;
    int* csr     = ip;  ip += EP;

    size_t needed = (size_t)((char*)ip - (char*)d_ws);
    if (needed > ws_size) return;  // loud failure if scratch too small

    hipMemsetAsync(deg, 0, (size_t)N * sizeof(int), stream);
    prep_kernel<<<1, 512, 0, stream>>>(W1, as1, ad1, W2, as2, ad2, wa1, wa2);
    xh1_kernel<<<(N * 120 + 255) / 256, 256, 0, stream>>>(x, W1, xh1h, N);
    a1_kernel<<<(N + 255) / 256, 256, 0, stream>>>(x, wa1, a_s1, a_d1, N);
    degree_kernel<<<(E + N + 255) / 256, 256, 0, stream>>>(ei, E, N, deg);
    scan2_kernel<<<1, 1024, 0, stream>>>(deg, row_ptr, cursor, N);
    scatter_kernel<<<(E + N + 255) / 256, 256, 0, stream>>>(ei, E, N, cursor, csr);
    gat1_pass_a<<<(N * 64 + 255) / 256, 256, 0, stream>>>(
        row_ptr, csr, a_s1, a_d1, pbuf1, inv1, N);
    gat1_pass_b<<<(N * 64 + 255) / 256, 256, 0, stream>>>(
        row_ptr, csr, pbuf1, inv1, xh1h, wa2, b1, hbuf, a_s2, a_d2, N);
    gemm2_kernel<<<(N + 127) / 128, 256, 0, stream>>>(hbuf, W2, xh2h, N);
    gat2_pass_a<<<(N * 64 + 255) / 256, 256, 0, stream>>>(
        row_ptr, csr, a_s2, a_d2, pbuf2, inv2, N);
    gat2_pass_b<<<(N * 64 + 255) / 256, 256, 0, stream>>>(
        row_ptr, csr, pbuf2, inv2, xh2h, b2, out, N);
}

// Round 4
// 438.200 us; speedup vs baseline: 1.4086x; 1.3690x over previous
//
#include <hip/hip_runtime.h>
#include <hip/hip_bf16.h>
#include <hip/hip_fp16.h>
#include <cstdint>
#include <cstddef>

// ---------------------------------------------------------------------------
// FeatureExtractorGAT, round 4.
// Changes vs R3 (measured: 600 us total, gat1_pass_b 151 us @ 43% HBM /
// 45% VALU / 75% occ -> latency-bound):
//  - gat1_pass_b / gat2_pass_b: edge loop unrolled x4 (batched csr loads ->
//    4 gathers in flight) for memory-latency hiding.
//  - gemm2: thread->row remap (i*16+ty instead of ty*8+i) kills the 4-way
//    LDS bank conflict on hv loads (old row stride 288 floats = bank 0 mod 32).
//  - single-block scan replaced by 3-kernel parallel scan (block scan ->
//    partials scan -> add offsets).
// ---------------------------------------------------------------------------

__global__ void prep_kernel(const float* __restrict__ W1,
                            const float* __restrict__ as1, const float* __restrict__ ad1,
                            const float* __restrict__ W2,
                            const float* __restrict__ as2, const float* __restrict__ ad2,
                            float* __restrict__ wa1, float* __restrict__ wa2)
{
    int t = threadIdx.x;
    if (t < 480) {
        float accs = 0.f, accd = 0.f;
        #pragma unroll 4
        for (int c = 0; c < 96; ++c) {
            float w = W2[t * 96 + c];
            accs += w * as2[c];
            accd += w * ad2[c];
        }
        wa2[t]       = accs;
        wa2[480 + t] = accd;
    }
    if (t < 32) {
        int k = t >> 3, h = t & 7;
        float accs = 0.f, accd = 0.f;
        for (int c = 0; c < 60; ++c) {
            float w = W1[k * 480 + h * 60 + c];
            accs += w * as1[h * 60 + c];
            accd += w * ad1[h * 60 + c];
        }
        wa1[k * 8 + h]      = accs;
        wa1[32 + k * 8 + h] = accd;
    }
}

// xh1h[n, j..j+3] (fp16): one float4-worth per thread
__global__ void xh1_kernel(const float* __restrict__ x, const float* __restrict__ W1,
                           __half* __restrict__ xh1h, int N)
{
    int idx = blockIdx.x * blockDim.x + threadIdx.x;
    if (idx >= N * 120) return;
    int n = idx / 120;
    int j = (idx - n * 120) * 4;
    float4 xv = *(const float4*)(x + (size_t)n * 4);
    float4 w0 = *(const float4*)(W1 + j);
    float4 w1 = *(const float4*)(W1 + 480 + j);
    float4 w2 = *(const float4*)(W1 + 960 + j);
    float4 w3 = *(const float4*)(W1 + 1440 + j);
    float ox = xv.x * w0.x + xv.y * w1.x + xv.z * w2.x + xv.w * w3.x;
    float oy = xv.x * w0.y + xv.y * w1.y + xv.z * w2.y + xv.w * w3.y;
    float oz = xv.x * w0.z + xv.y * w1.z + xv.z * w2.z + xv.w * w3.z;
    float ow = xv.x * w0.w + xv.y * w1.w + xv.z * w2.w + xv.w * w3.w;
    __half2* dst = (__half2*)(xh1h + (size_t)n * 480 + j);
    dst[0] = __floats2half2_rn(ox, oy);
    dst[1] = __floats2half2_rn(oz, ow);
}

__global__ void a1_kernel(const float* __restrict__ x, const float* __restrict__ wa1,
                          float* __restrict__ a_s1, float* __restrict__ a_d1, int N)
{
    int n = blockIdx.x * blockDim.x + threadIdx.x;
    if (n >= N) return;
    float4 xv = *(const float4*)(x + (size_t)n * 4);
    #pragma unroll
    for (int h = 0; h < 8; ++h) {
        float as = xv.x * wa1[h] + xv.y * wa1[8 + h] + xv.z * wa1[16 + h] + xv.w * wa1[24 + h];
        float ad = xv.x * wa1[32 + h] + xv.y * wa1[40 + h] + xv.z * wa1[48 + h] + xv.w * wa1[56 + h];
        a_s1[n * 8 + h] = as;
        a_d1[n * 8 + h] = ad;
    }
}

__global__ void degree_kernel(const int* __restrict__ ei, int E, int N, int* __restrict__ deg)
{
    int e = blockIdx.x * blockDim.x + threadIdx.x;
    if (e >= E + N) return;
    int d = (e < E) ? ei[E + e] : (e - E);
    atomicAdd(&deg[d], 1);
}

// ---- parallel scan: block-local exclusive scan + block partial
__global__ __launch_bounds__(1024) void scan_blk_kernel(const int* __restrict__ deg, int N,
                                                        int* __restrict__ row_ptr,
                                                        int* __restrict__ partials)
{
    __shared__ int wsum[16];
    int i = blockIdx.x * 1024 + threadIdx.x;
    int lane = threadIdx.x & 63, wid = threadIdx.x >> 6;
    int v = (i < N) ? deg[i] : 0;
    int x = v;
    #pragma unroll
    for (int off = 1; off < 64; off <<= 1) {
        int y = __shfl_up(x, off, 64);
        if (lane >= off) x += y;
    }
    if (lane == 63) wsum[wid] = x;
    __syncthreads();
    if (wid == 0) {
        int wv = (lane < 16) ? wsum[lane] : 0;
        #pragma unroll
        for (int off = 1; off < 16; off <<= 1) {
            int y = __shfl_up(wv, off, 64);
            if (lane >= off) wv += y;
        }
        if (lane < 16) wsum[lane] = wv;
    }
    __syncthreads();
    int excl = (wid ? wsum[wid - 1] : 0) + x - v;
    if (i < N) row_ptr[i] = excl;
    if (threadIdx.x == 1023) partials[blockIdx.x] = wsum[15];
}

// ---- scan of block partials (nb <= 64) + write row_ptr[N] = total
__global__ void scan_part_kernel(int* __restrict__ partials, int nb,
                                 int* __restrict__ row_ptr, int N)
{
    int lane = threadIdx.x & 63;
    int v = (lane < nb) ? partials[lane] : 0;
    int x = v;
    #pragma unroll
    for (int off = 1; off < 64; off <<= 1) {
        int y = __shfl_up(x, off, 64);
        if (lane >= off) x += y;
    }
    if (lane < nb) partials[lane] = x - v;   // exclusive block offsets
    if (lane == 63) row_ptr[N] = x;          // grand total
}

// ---- add block offsets, produce cursor copy
__global__ __launch_bounds__(1024) void scan_add_kernel(int* __restrict__ row_ptr,
                                                        const int* __restrict__ partials,
                                                        int* __restrict__ cursor, int N)
{
    int i = blockIdx.x * 1024 + threadIdx.x;
    if (i < N) {
        int r = row_ptr[i] + partials[blockIdx.x];
        row_ptr[i] = r;
        cursor[i]  = r;
    }
}

__global__ void scatter_kernel(const int* __restrict__ ei, int E, int N,
                               int* __restrict__ cursor, int* __restrict__ csr)
{
    int e = blockIdx.x * blockDim.x + threadIdx.x;
    if (e >= E + N) return;
    int s, d;
    if (e < E) { s = ei[e]; d = ei[E + e]; } else { s = d = e - E; }
    int pos = atomicAdd(&cursor[d], 1);
    csr[pos] = s;
}

// ---- GAT layer 1, phase A: p[e][h] = exp(leaky(a_s[src]+a_d[dst])), per-node sums
__global__ __launch_bounds__(256) void gat1_pass_a(
    const int* __restrict__ row_ptr, const int* __restrict__ csr,
    const float* __restrict__ a_s1, const float* __restrict__ a_d1,
    float* __restrict__ pbuf1, float* __restrict__ inv1, int N)
{
    int gid = blockIdx.x * blockDim.x + threadIdx.x;
    int node = gid >> 6;
    if (node >= N) return;
    int lane = threadIdx.x & 63;
    float4 adA = *(const float4*)(a_d1 + (size_t)node * 8);
    float4 adB = *(const float4*)(a_d1 + (size_t)node * 8 + 4);
    float ad[8] = {adA.x, adA.y, adA.z, adA.w, adB.x, adB.y, adB.z, adB.w};
    float s[8] = {0.f, 0.f, 0.f, 0.f, 0.f, 0.f, 0.f, 0.f};
    int beg = row_ptr[node], end = row_ptr[node + 1];
    for (int e = beg + lane; e < end; e += 64) {
        int src = csr[e];
        float4 asA = *(const float4*)(a_s1 + (size_t)src * 8);
        float4 asB = *(const float4*)(a_s1 + (size_t)src * 8 + 4);
        float as[8] = {asA.x, asA.y, asA.z, asA.w, asB.x, asB.y, asB.z, asB.w};
        float p[8];
        #pragma unroll
        for (int h = 0; h < 8; ++h) {
            float ev = as[h] + ad[h];
            ev = ev > 0.f ? ev : 0.2f * ev;
            float pv = __expf(ev);
            p[h] = pv;
            s[h] += pv;
        }
        float4* pp = (float4*)(pbuf1 + (size_t)e * 8);
        pp[0] = make_float4(p[0], p[1], p[2], p[3]);
        pp[1] = make_float4(p[4], p[5], p[6], p[7]);
    }
    #pragma unroll
    for (int h = 0; h < 8; ++h) {
        #pragma unroll
        for (int off = 32; off; off >>= 1) s[h] += __shfl_xor(s[h], off);
    }
    if (lane == 0) {
        float* ip = inv1 + (size_t)node * 8;
        #pragma unroll
        for (int h = 0; h < 8; ++h) ip[h] = 1.f / (s[h] + 1e-16f);
    }
}

// ---- GAT layer 1, phase B: weighted aggregate + bias + ELU + layer-2 dots.
// Lane l<60 owns 8 contiguous features [8l, 8l+8) -> one 16B fp16 load/edge.
// Edge loop unrolled x4: batch the csr loads so 4 gathers are in flight.
__global__ __launch_bounds__(256) void gat1_pass_b(
    const int* __restrict__ row_ptr, const int* __restrict__ csr,
    const float* __restrict__ pbuf1, const float* __restrict__ inv1,
    const __half* __restrict__ xh1h, const float* __restrict__ wa2,
    const float* __restrict__ b1,
    float* __restrict__ hout, float* __restrict__ a2s, float* __restrict__ a2d, int N)
{
    int gid = blockIdx.x * blockDim.x + threadIdx.x;
    int node = gid >> 6;
    if (node >= N) return;
    int lane = threadIdx.x & 63;
    bool act = lane < 60;
    int col0 = act ? lane * 8 : 0;
    int hA = col0 / 60;
    int hB = (col0 + 7) / 60;
    int sb = 60 * (hA + 1) - col0;  if (sb > 8) sb = 8;  // cols j<sb belong to head hA
    const float* ip = inv1 + (size_t)node * 8;
    float invA = ip[hA], invB = ip[hB];

    float acc[8];
    #pragma unroll
    for (int j = 0; j < 8; ++j) acc[j] = 0.f;

    int beg = row_ptr[node], end = row_ptr[node + 1];
    int e = beg;
    constexpr int U = 4;
    for (; e + U <= end; e += U) {
        int srcs[U];
        #pragma unroll
        for (int u = 0; u < U; ++u) srcs[u] = csr[e + u];
        uint4 raw[U];
        #pragma unroll
        for (int u = 0; u < U; ++u)
            raw[u] = *(const uint4*)(xh1h + (size_t)srcs[u] * 480 + col0);
        float cc[U][2];
        #pragma unroll
        for (int u = 0; u < U; ++u) {
            const float* pr = pbuf1 + (size_t)(e + u) * 8;
            cc[u][0] = pr[hA] * invA;
            cc[u][1] = pr[hB] * invB;
        }
        #pragma unroll
        for (int u = 0; u < U; ++u) {
            float2 f0 = __half22float2(*(const __half2*)&raw[u].x);
            float2 f1 = __half22float2(*(const __half2*)&raw[u].y);
            float2 f2 = __half22float2(*(const __half2*)&raw[u].z);
            float2 f3 = __half22float2(*(const __half2*)&raw[u].w);
            float g[8] = {f0.x, f0.y, f1.x, f1.y, f2.x, f2.y, f3.x, f3.y};
            #pragma unroll
            for (int j = 0; j < 8; ++j)
                acc[j] += ((j < sb) ? cc[u][0] : cc[u][1]) * g[j];
        }
    }
    for (; e < end; ++e) {
        int src = csr[e];
        const float* pr = pbuf1 + (size_t)e * 8;
        float cA = pr[hA] * invA;
        float cB = pr[hB] * invB;
        uint4 raw = *(const uint4*)(xh1h + (size_t)src * 480 + col0);
        float2 f0 = __half22float2(*(const __half2*)&raw.x);
        float2 f1 = __half22float2(*(const __half2*)&raw.y);
        float2 f2 = __half22float2(*(const __half2*)&raw.z);
        float2 f3 = __half22float2(*(const __half2*)&raw.w);
        float g[8] = {f0.x, f0.y, f1.x, f1.y, f2.x, f2.y, f3.x, f3.y};
        #pragma unroll
        for (int j = 0; j < 8; ++j)
            acc[j] += ((j < sb) ? cA : cB) * g[j];
    }

    float psrc = 0.f, pdst = 0.f;
    if (act) {
        float o[8];
        #pragma unroll
        for (int j = 0; j < 8; ++j) {
            float v = acc[j] + b1[col0 + j];
            o[j] = v > 0.f ? v : expm1f(v);
        }
        float4* hp = (float4*)(hout + (size_t)node * 480 + col0);
        hp[0] = make_float4(o[0], o[1], o[2], o[3]);
        hp[1] = make_float4(o[4], o[5], o[6], o[7]);
        #pragma unroll
        for (int j = 0; j < 8; ++j) {
            psrc += o[j] * wa2[col0 + j];
            pdst += o[j] * wa2[480 + col0 + j];
        }
    }
    #pragma unroll
    for (int off = 32; off; off >>= 1) {
        psrc += __shfl_xor(psrc, off);
        pdst += __shfl_xor(pdst, off);
    }
    if (lane == 0) { a2s[node] = psrc; a2d[node] = pdst; }
}

// ---- GAT layer 2, phase A (1 head)
__global__ __launch_bounds__(256) void gat2_pass_a(
    const int* __restrict__ row_ptr, const int* __restrict__ csr,
    const float* __restrict__ a_s2, const float* __restrict__ a_d2,
    float* __restrict__ pbuf2, float* __restrict__ inv2, int N)
{
    int gid = blockIdx.x * blockDim.x + threadIdx.x;
    int node = gid >> 6;
    if (node >= N) return;
    int lane = threadIdx.x & 63;
    float adv = a_d2[node];
    float s = 0.f;
    int beg = row_ptr[node], end = row_ptr[node + 1];
    for (int e = beg + lane; e < end; e += 64) {
        int src = csr[e];
        float ev = a_s2[src] + adv;
        ev = ev > 0.f ? ev : 0.2f * ev;
        float pv = __expf(ev);
        pbuf2[e] = pv;
        s += pv;
    }
    #pragma unroll
    for (int off = 32; off; off >>= 1) s += __shfl_xor(s, off);
    if (lane == 0) inv2[node] = 1.f / (s + 1e-16f);
}

// ---- GAT layer 2, phase B: lane<48 owns cols {2l, 2l+1}; unrolled x4.
__global__ __launch_bounds__(256) void gat2_pass_b(
    const int* __restrict__ row_ptr, const int* __restrict__ csr,
    const float* __restrict__ pbuf2, const float* __restrict__ inv2,
    const __half* __restrict__ xh2h, const float* __restrict__ b2,
    float* __restrict__ out, int N)
{
    int gid = blockIdx.x * blockDim.x + threadIdx.x;
    int node = gid >> 6;
    if (node >= N) return;
    int lane = threadIdx.x & 63;
    bool act = lane < 48;
    float invv = inv2[node];
    float ax = 0.f, ay = 0.f;
    int beg = row_ptr[node], end = row_ptr[node + 1];
    int e = beg;
    constexpr int U = 4;
    for (; e + U <= end; e += U) {
        int srcs[U]; float ps[U];
        #pragma unroll
        for (int u = 0; u < U; ++u) srcs[u] = csr[e + u];
        #pragma unroll
        for (int u = 0; u < U; ++u) ps[u] = pbuf2[e + u];
        if (act) {
            __half2 gv[U];
            #pragma unroll
            for (int u = 0; u < U; ++u)
                gv[u] = ((const __half2*)(xh2h + (size_t)srcs[u] * 96))[lane];
            #pragma unroll
            for (int u = 0; u < U; ++u) {
                float c = ps[u] * invv;
                float2 fg = __half22float2(gv[u]);
                ax += c * fg.x;
                ay += c * fg.y;
            }
        }
    }
    for (; e < end; ++e) {
        int src = csr[e];
        float c = pbuf2[e] * invv;
        if (act) {
            __half2 g = ((const __half2*)(xh2h + (size_t)src * 96))[lane];
            float2 fg = __half22float2(g);
            ax += c * fg.x;
            ay += c * fg.y;
        }
    }
    if (act) {
        out[(size_t)node * 96 + 2 * lane]     = ax + b2[2 * lane];
        out[(size_t)node * 96 + 2 * lane + 1] = ay + b2[2 * lane + 1];
    }
}

// xh2h[N,96] = h[N,480] @ W2[480,96], fp16 out.
// Thread t = (ty, tx): rows {i*16+ty} (conflict-free LDS: row diff 36 = bank+4),
// cols {tx*6+j}.
__global__ __launch_bounds__(256) void gemm2_kernel(
    const float* __restrict__ h, const float* __restrict__ W2,
    __half* __restrict__ xh2h, int N)
{
    __shared__ float hs[128][36];
    __shared__ float ws[32][96];
    int t = threadIdx.x;
    int nbase = blockIdx.x * 128;
    int tx = t & 15, ty = t >> 4;
    float acc[8][6];
    #pragma unroll
    for (int i = 0; i < 8; ++i)
        #pragma unroll
        for (int j = 0; j < 6; ++j) acc[i][j] = 0.f;

    for (int k0 = 0; k0 < 480; k0 += 32) {
        #pragma unroll
        for (int i = 0; i < 3; ++i) {
            int f = i * 256 + t;
            int kk = f / 24, c4 = f % 24;
            float4 v = *(const float4*)(W2 + (size_t)(k0 + kk) * 96 + c4 * 4);
            *(float4*)&ws[kk][c4 * 4] = v;
        }
        #pragma unroll
        for (int i = 0; i < 4; ++i) {
            int f = i * 256 + t;
            int node = f >> 3, k4 = f & 7;
            int gn = nbase + node; if (gn > N - 1) gn = N - 1;
            float4 v = *(const float4*)(h + (size_t)gn * 480 + k0 + k4 * 4);
            *(float4*)&hs[node][k4 * 4] = v;
        }
        __syncthreads();
        #pragma unroll
        for (int kk = 0; kk < 32; ++kk) {
            float hv[8], wv[6];
            #pragma unroll
            for (int i = 0; i < 8; ++i) hv[i] = hs[i * 16 + ty][kk];
            #pragma unroll
            for (int j = 0; j < 6; ++j) wv[j] = ws[kk][tx * 6 + j];
            #pragma unroll
            for (int i = 0; i < 8; ++i)
                #pragma unroll
                for (int j = 0; j < 6; ++j)
                    acc[i][j] += hv[i] * wv[j];
        }
        __syncthreads();
    }
    #pragma unroll
    for (int i = 0; i < 8; ++i) {
        int gn = nbase + i * 16 + ty;
        if (gn < N) {
            #pragma unroll
            for (int j = 0; j < 6; ++j)
                xh2h[(size_t)gn * 96 + tx * 6 + j] = __float2half(acc[i][j]);
        }
    }
}

extern "C" void kernel_launch(void* const* d_in, const int* in_sizes, int n_in,
                              void* d_out, int out_size, void* d_ws, size_t ws_size,
                              hipStream_t stream)
{
    const float* x   = (const float*)d_in[0];
    const int*   ei  = (const int*)  d_in[1];
    const float* W1  = (const float*)d_in[2];
    const float* as1 = (const float*)d_in[3];
    const float* ad1 = (const float*)d_in[4];
    const float* b1  = (const float*)d_in[5];
    const float* W2  = (const float*)d_in[6];
    const float* as2 = (const float*)d_in[7];
    const float* ad2 = (const float*)d_in[8];
    const float* b2  = (const float*)d_in[9];
    float* out = (float*)d_out;

    int N  = in_sizes[0] / 4;   // 50000
    int E  = in_sizes[1] / 2;   // 800000
    int EP = E + N;
    int NB = (N + 1023) / 1024; // scan blocks (<= 64 required; 49 here)

    float* f = (float*)d_ws;
    float* hbuf  = f;  f += (size_t)N * 480;
    float* a_s1  = f;  f += (size_t)N * 8;
    float* a_d1  = f;  f += (size_t)N * 8;
    float* inv1  = f;  f += (size_t)N * 8;
    float* a_s2  = f;  f += N;
    float* a_d2  = f;  f += N;
    float* inv2  = f;  f += N;
    float* wa1   = f;  f += 64;
    float* wa2   = f;  f += 960;
    float* pbuf1 = f;  f += (size_t)EP * 8;
    float* pbuf2 = f;  f += EP;
    __half* xh1h = (__half*)f;
    __half* hp   = xh1h + (size_t)N * 480;
    __half* xh2h = hp;   hp += (size_t)N * 96;
    int* ip      = (int*)hp;
    int* row_ptr = ip;  ip += N + 1;
    int* deg     = ip;  ip += N;
    int* cursor  = ip;  ip += N;
    int* partials= ip;  ip += 64;
    int* csr     = ip;  ip += EP;

    size_t needed = (size_t)((char*)ip - (char*)d_ws);
    if (needed > ws_size) return;  // loud failure if scratch too small

    hipMemsetAsync(deg, 0, (size_t)N * sizeof(int), stream);
    prep_kernel<<<1, 512, 0, stream>>>(W1, as1, ad1, W2, as2, ad2, wa1, wa2);
    xh1_kernel<<<(N * 120 + 255) / 256, 256, 0, stream>>>(x, W1, xh1h, N);
    a1_kernel<<<(N + 255) / 256, 256, 0, stream>>>(x, wa1, a_s1, a_d1, N);
    degree_kernel<<<(E + N + 255) / 256, 256, 0, stream>>>(ei, E, N, deg);
    scan_blk_kernel<<<NB, 1024, 0, stream>>>(deg, N, row_ptr, partials);
    scan_part_kernel<<<1, 64, 0, stream>>>(partials, NB, row_ptr, N);
    scan_add_kernel<<<NB, 1024, 0, stream>>>(row_ptr, partials, cursor, N);
    scatter_kernel<<<(E + N + 255) / 256, 256, 0, stream>>>(ei, E, N, cursor, csr);
    gat1_pass_a<<<(N * 64 + 255) / 256, 256, 0, stream>>>(
        row_ptr, csr, a_s1, a_d1, pbuf1, inv1, N);
    gat1_pass_b<<<(N * 64 + 255) / 256, 256, 0, stream>>>(
        row_ptr, csr, pbuf1, inv1, xh1h, wa2, b1, hbuf, a_s2, a_d2, N);
    gemm2_kernel<<<(N + 127) / 128, 256, 0, stream>>>(hbuf, W2, xh2h, N);
    gat2_pass_a<<<(N * 64 + 255) / 256, 256, 0, stream>>>(
        row_ptr, csr, a_s2, a_d2, pbuf2, inv2, N);
    gat2_pass_b<<<(N * 64 + 255) / 256, 256, 0, stream>>>(
        row_ptr, csr, pbuf2, inv2, xh2h, b2, out, N);
}